// Round 14
// baseline (375.106 us; speedup 1.0000x reference)
//
#include <hip/hip_runtime.h>

// Acoustic stress-velocity FD propagator, MI355X — persistent kernel v14.
// v13 (TS=16, proven all-far sc0 sc1 protocol) with 2x4 thread patches:
// each thread owns TWO adjacent x-rows (8 cells), so the x-neighbor that
// needed LDS is in-register for half the cells. Per thread-step DS: read
// p(R2), read vx(R0-1), write vx(R1), write p(R0),p(R1) = 5 b128 per 8
// cells (vs 4 per 4 cells in v13) -> DS/CU/step -40%. p stays fully in LDS
// so receivers (incl. duplicate rcv_x) work as in v13. Sync protocol
// bit-identical to v13. Row pairs start even -> never straddle the domain
// edge. Shuffle wrong-lane values land only on region-edge cells z=0/63
// (trapezoid garbage ring); domain z-boundary masked by bz/dkz coeffs.

#define NXc 256
#define NZc 256
#define NTc 400
#define NSc 4
#define NRc 128

#define TS 16                   // steps per epoch = halo depth
#define Bt 32                   // tile edge
#define LROW 64                 // region edge (z)
#define ROWS 64                 // region edge (x)
#define TR 32                   // thread-rows (2 x-rows each)
#define NSTR 16                 // 4-wide strips per row
#define BT 512                  // threads = 32 thread-rows x 16 strips
#define SPSZ ((ROWS + 2) * LROW) // 4224 (p: all rows + top/bottom pad)
#define SVSZ ((TR + 1) * LROW)   // 2112 (vx of odd rows + top pad)
#define NBLK (NSc * 64)         // 256 blocks
#define NEP (NTc / TS)          // 25 epochs

constexpr float DT_H    = 0.001f;
constexpr float INV_D   = 0.1f;            // 1/DX = 1/DZ
constexpr float SRC_AMP = 0.001f * 0.01f;  // DT/(DX*DZ)
constexpr int   NXZ     = NXc * NZc;

typedef float f32x4 __attribute__((ext_vector_type(4)));

__device__ __forceinline__ unsigned ldu_far(const unsigned* p) {
    unsigned v;
    asm volatile("global_load_dword %0, %1, off sc0 sc1\n\t"
                 "s_waitcnt vmcnt(0)" : "=&v"(v) : "v"(p) : "memory");
    return v;
}
__device__ __forceinline__ void stu_far(unsigned* p, unsigned v) {
    asm volatile("global_store_dword %0, %1, off sc0 sc1"
                 :: "v"(p), "v"(v) : "memory");
}

__global__ __launch_bounds__(BT) void prop_kernel(
    float* __restrict__ xchg, unsigned* __restrict__ flags,
    const float* __restrict__ vp, const float* __restrict__ rho,
    const float* __restrict__ damp, const float* __restrict__ wavelet,
    const int* __restrict__ src_x, const int* __restrict__ src_z,
    const int* __restrict__ rcv_x, const int* __restrict__ rcv_z,
    float* __restrict__ out)
{
    __shared__ float sp[SPSZ];   // p, all 64 region rows (+2 pad rows)
    __shared__ float svo[SVSZ];  // vx of odd region rows (+ top pad row)

    const int tid  = threadIdx.x;
    const int bid  = blockIdx.x;
    const int s    = bid >> 6;
    const int tile = bid & 63;
    const int tx = tile >> 3, tz = tile & 7;
    const int gx0 = tx * Bt - TS, gz0 = tz * Bt - TS;

    const int li2 = tid >> 4;              // thread-row 0..31
    const int st  = tid & 15;              // strip 0..15
    const int lk0 = st * 4;
    const int gi0 = gx0 + 2 * li2;         // even; rows gi0, gi0+1
    const int gk0 = gz0 + lk0;
    const bool in = ((unsigned)gi0 < (unsigned)NXc) &&
                    ((unsigned)gk0 < (unsigned)NZc);
    const int c40 = s * NXZ + gi0 * NZc + gk0;    // row R0 global idx
    const bool central = in && ((unsigned)(li2 - 8) < 16u)
                            && (st >= 4) && (st < 12);
    const bool ring = in && !central;

    const size_t F = (size_t)NSc * NXZ;
    float* b0 = xchg;            // epoch parity 0: {p, vx, vz}
    float* b1 = xchg + 3 * F;    // epoch parity 1

    // ---- per-cell time-invariant coefficients + state (registers) ----
    float pr[2][4]  = {{0,0,0,0},{0,0,0,0}};
    float vxr[2][4] = {{0,0,0,0},{0,0,0,0}};
    float vzr[2][4] = {{0,0,0,0},{0,0,0,0}};
    float fr[2][4], bxr[2][4], bzr[2][4], dkxr[2][4], dkzr[2][4], sfr[2][4];
    {
        const int sx = src_x[s], sz = src_z[s];
#pragma unroll
        for (int r = 0; r < 2; ++r) {
            const int gi = gi0 + r;
            if (in) {
                const int g = gi * NZc + gk0;
                float4 r4 = *(const float4*)(rho  + g);
                float4 v4 = *(const float4*)(vp   + g);
                float4 d4 = *(const float4*)(damp + g);
                float rv[4] = {r4.x, r4.y, r4.z, r4.w};
                float vv[4] = {v4.x, v4.y, v4.z, v4.w};
                float dv[4] = {d4.x, d4.y, d4.z, d4.w};
#pragma unroll
                for (int k = 0; k < 4; ++k) {
                    int gk = gk0 + k;
                    fr[r][k] = 1.0f - DT_H * dv[k];
                    float bi = DT_H / rv[k] * INV_D;
                    bxr[r][k] = (gi == NXc - 1) ? 0.f : bi;  // _dxf pad
                    bzr[r][k] = (gk == NZc - 1) ? 0.f : bi;  // _dzf pad
                    float dk = DT_H * rv[k] * vv[k] * vv[k] * INV_D;
                    dkxr[r][k] = (gi == 0) ? 0.f : dk;       // _dxb pad
                    dkzr[r][k] = (gk == 0) ? 0.f : dk;       // _dzb pad
                    sfr[r][k]  = (gi == sx && gk == sz) ? SRC_AMP : 0.f;
                }
            } else {
#pragma unroll
                for (int k = 0; k < 4; ++k) {
                    fr[r][k]=0.f; bxr[r][k]=0.f; bzr[r][k]=0.f;
                    dkxr[r][k]=0.f; dkzr[r][k]=0.f; sfr[r][k]=0.f;
                }
            }
        }
    }

    // LDS indices. sp row R lives at (R+1)*LROW; my rows R0=2li2, R1=2li2+1.
    const int jp0 = (2 * li2 + 1) * LROW + lk0;   // p(R0)
    const int jvo = (li2 + 1) * LROW + lk0;       // vx(R1) slot

    // Pads (never overwritten: steps write rows 0..63 / svo rows 1..32).
    if (tid < LROW) {
        sp[tid] = 0.f;                       // sp row -1
        sp[SPSZ - LROW + tid] = 0.f;         // sp row 64
        svo[tid] = 0.f;                      // svo top pad (vx row -1)
    }
    // Initial LDS state (zeros).
    *(f32x4*)&sp[jp0] = f32x4{0,0,0,0};
    *(f32x4*)&sp[jp0 + LROW] = f32x4{0,0,0,0};
    *(f32x4*)&svo[jvo] = f32x4{0,0,0,0};

    // Receivers (loaded once).
    int rxv = 0, rzv = 0;
    if (tid < NRc) { rxv = rcv_x[tid]; rzv = rcv_z[tid]; }
    const bool rown = (tid < NRc) &&
        ((unsigned)(rxv - tx * Bt) < (unsigned)Bt) &&
        ((unsigned)(rzv - tz * Bt) < (unsigned)Bt);
    const int rj = (rxv - gx0 + 1) * LROW + (rzv - gz0);
    float* obase = out + (size_t)s * NTc * NRc + tid;
    const float* wb = wavelet + s * NTc;

    // Proxy-poll neighbor (tids 0..8, minus center 4).
    int nbid = -1;
    if (tid < 9 && tid != 4) {
        int dx = tid / 3 - 1, dz = tid - (tid / 3) * 3 - 1;
        int nx2 = tx + dx, nz2 = tz + dz;
        if (((unsigned)nx2 < 8u) && ((unsigned)nz2 < 8u))
            nbid = (s << 6) + nx2 * 8 + nz2;
    }

    for (int l = 0; l < NEP; ++l) {
        const bool notLast = (l < NEP - 1);
        float* pb = (l & 1) ? b1 : b0;
        __syncthreads();   // orders init / ring-reload LDS writes

        for (int tau = 0; tau < TS; ++tau) {
            // ---- velocity: reads sp + regs, writes svo ----
            f32x4 pn = *(const f32x4*)&sp[jp0 + 2 * LROW];  // p(R2)
            float pze0 = __shfl_down(pr[0][0], 1, 64);      // next strip
            float pze1 = __shfl_down(pr[1][0], 1, 64);
            // r0: x-neighbor p(R1) in-register; r1: p(R2) from LDS.
            {
                float pz1a[4] = {pr[0][1], pr[0][2], pr[0][3], pze0};
                float pz1b[4] = {pr[1][1], pr[1][2], pr[1][3], pze1};
#pragma unroll
                for (int k = 0; k < 4; ++k) {
                    vxr[0][k] = fr[0][k]*vxr[0][k]
                              - bxr[0][k]*(pr[1][k] - pr[0][k]);
                    vzr[0][k] = fr[0][k]*vzr[0][k]
                              - bzr[0][k]*(pz1a[k] - pr[0][k]);
                    vxr[1][k] = fr[1][k]*vxr[1][k]
                              - bxr[1][k]*(pn[k] - pr[1][k]);
                    vzr[1][k] = fr[1][k]*vzr[1][k]
                              - bzr[1][k]*(pz1b[k] - pr[1][k]);
                }
            }
            *(f32x4*)&svo[jvo] =
                f32x4{vxr[1][0], vxr[1][1], vxr[1][2], vxr[1][3]};
            __syncthreads();

            // ---- pressure: reads svo + regs, writes sp ----
            const float wv = wb[l * TS + tau];
            f32x4 vxm = *(const f32x4*)&svo[jvo - LROW];    // vx(R0-1)
            float vzm0 = __shfl_up(vzr[0][3], 1, 64);       // prev strip
            float vzm1 = __shfl_up(vzr[1][3], 1, 64);
            {
                float vza[4] = {vzm0, vzr[0][0], vzr[0][1], vzr[0][2]};
                float vzb[4] = {vzm1, vzr[1][0], vzr[1][1], vzr[1][2]};
#pragma unroll
                for (int k = 0; k < 4; ++k) {
                    pr[0][k] = fr[0][k]*pr[0][k]
                             - dkxr[0][k]*(vxr[0][k] - vxm[k])
                             - dkzr[0][k]*(vzr[0][k] - vza[k])
                             + sfr[0][k]*wv;
                    pr[1][k] = fr[1][k]*pr[1][k]
                             - dkxr[1][k]*(vxr[1][k] - vxr[0][k])
                             - dkzr[1][k]*(vzr[1][k] - vzb[k])
                             + sfr[1][k]*wv;
                }
            }
            // Publish overlapped: MALL stores as soon as final pr known.
            if (tau == TS - 1 && notLast && central) {
                f32x4 pa = {pr[0][0], pr[0][1], pr[0][2], pr[0][3]};
                f32x4 pc = {pr[1][0], pr[1][1], pr[1][2], pr[1][3]};
                f32x4 xa = {vxr[0][0], vxr[0][1], vxr[0][2], vxr[0][3]};
                f32x4 xc = {vxr[1][0], vxr[1][1], vxr[1][2], vxr[1][3]};
                f32x4 za = {vzr[0][0], vzr[0][1], vzr[0][2], vzr[0][3]};
                f32x4 zc = {vzr[1][0], vzr[1][1], vzr[1][2], vzr[1][3]};
                asm volatile(
                    "global_store_dwordx4 %0, %6, off sc0 sc1\n\t"
                    "global_store_dwordx4 %1, %7, off sc0 sc1\n\t"
                    "global_store_dwordx4 %2, %8, off sc0 sc1\n\t"
                    "global_store_dwordx4 %3, %9, off sc0 sc1\n\t"
                    "global_store_dwordx4 %4, %10, off sc0 sc1\n\t"
                    "global_store_dwordx4 %5, %11, off sc0 sc1"
                    :: "v"(pb + c40), "v"(pb + c40 + NZc),
                       "v"(pb + F + c40), "v"(pb + F + c40 + NZc),
                       "v"(pb + 2*F + c40), "v"(pb + 2*F + c40 + NZc),
                       "v"(pa), "v"(pc), "v"(xa), "v"(xc), "v"(za), "v"(zc)
                    : "memory");
            }
            *(f32x4*)&sp[jp0] =
                f32x4{pr[0][0], pr[0][1], pr[0][2], pr[0][3]};
            *(f32x4*)&sp[jp0 + LROW] =
                f32x4{pr[1][0], pr[1][1], pr[1][2], pr[1][3]};
            __syncthreads();

            // Receiver record taus 0..TS-2 (last tau below, overlapped).
            if (tau < TS - 1 && rown)
                obase[(size_t)(l * TS + tau) * NRc] = sp[rj];
        }

        if (notLast) {
            // Release: drain publish stores, then flag.
            asm volatile("s_waitcnt vmcnt(0)" ::: "memory");
            __syncthreads();
            if (tid == 0) stu_far(flags + bid, (unsigned)(l + 1));
            // last-tau receiver record overlaps the polls.
            if (rown) obase[(size_t)(l * TS + TS - 1) * NRc] = sp[rj];
            // Proxy poll: 8 threads watch the 8 neighbors.
            if (nbid >= 0) {
                const unsigned want = (unsigned)(l + 1);
                const unsigned* fp = flags + nbid;
                while (ldu_far(fp) < want) __builtin_amdgcn_s_sleep(2);
            }
            __syncthreads();
            // Ring reload -> regs + LDS. Central strips' sp/svo already
            // hold last-tau values; loop-top barrier orders LDS writes.
            if (ring) {
                f32x4 pa, pc, xa, xc, za, zc;
                asm volatile(
                    "global_load_dwordx4 %0, %6, off sc0 sc1\n\t"
                    "global_load_dwordx4 %1, %7, off sc0 sc1\n\t"
                    "global_load_dwordx4 %2, %8, off sc0 sc1\n\t"
                    "global_load_dwordx4 %3, %9, off sc0 sc1\n\t"
                    "global_load_dwordx4 %4, %10, off sc0 sc1\n\t"
                    "global_load_dwordx4 %5, %11, off sc0 sc1\n\t"
                    "s_waitcnt vmcnt(0)"
                    : "=&v"(pa), "=&v"(pc), "=&v"(xa), "=&v"(xc),
                      "=&v"(za), "=&v"(zc)
                    : "v"(pb + c40), "v"(pb + c40 + NZc),
                      "v"(pb + F + c40), "v"(pb + F + c40 + NZc),
                      "v"(pb + 2*F + c40), "v"(pb + 2*F + c40 + NZc)
                    : "memory");
#pragma unroll
                for (int k = 0; k < 4; ++k) {
                    pr[0][k] = pa[k];  pr[1][k] = pc[k];
                    vxr[0][k] = xa[k]; vxr[1][k] = xc[k];
                    vzr[0][k] = za[k]; vzr[1][k] = zc[k];
                }
                *(f32x4*)&sp[jp0] = pa;
                *(f32x4*)&sp[jp0 + LROW] = pc;
                *(f32x4*)&svo[jvo] = xc;
            }
        } else {
            if (rown) obase[(size_t)(l * TS + TS - 1) * NRc] = sp[rj];
        }
    }
}

extern "C" void kernel_launch(void* const* d_in, const int* in_sizes, int n_in,
                              void* d_out, int out_size, void* d_ws, size_t ws_size,
                              hipStream_t stream)
{
    const float* vp      = (const float*)d_in[0];
    const float* rho     = (const float*)d_in[1];
    const float* damp    = (const float*)d_in[2];
    const float* wavelet = (const float*)d_in[3];
    const int*   src_x   = (const int*)d_in[4];
    const int*   src_z   = (const int*)d_in[5];
    const int*   rcv_x   = (const int*)d_in[6];
    const int*   rcv_z   = (const int*)d_in[7];
    float* out = (float*)d_out;
    float* ws  = (float*)d_ws;

    const size_t F = (size_t)NSc * NXZ;
    float* xchg = ws;                              // 6 fields (2 parities)
    unsigned* flags = (unsigned*)(ws + 6 * F);     // 256 epoch counters

    // Flags must start at 0 every call (ws poisoned once, not re-poisoned).
    hipMemsetAsync(flags, 0, NBLK * sizeof(unsigned), stream);

    prop_kernel<<<NBLK, BT, 0, stream>>>(
        xchg, flags, vp, rho, damp, wavelet,
        src_x, src_z, rcv_x, rcv_z, out);
}

// Round 15
// 285.995 us; speedup vs baseline: 1.3116x; 1.3116x over previous
//
#include <hip/hip_runtime.h>

// Acoustic stress-velocity FD propagator, MI355X — persistent kernel v15.
// v13 (TS=16, 1024 thr, proven all-far sc0 sc1 protocol) with the two
// barrier-phases FUSED into one: each thread keeps register SHADOWS of the
// neighbor velocities it needs (vxm[4] = row R-1's vx, updated with row
// R-1's own coefficients and the same p inputs -> bit-identical; vzm =
// prev strip's vz[3] via shfl of old p). p is double-buffered in LDS
// (read old buffer, write new buffer) -> no intra-phase hazard -> ONE
// barrier + 3 b128 + 2 swizzles per step (v13: 2 barriers + 4 b128 + 2).
// v14's lesson applied: keep 16 waves/CU for latency hiding. Sync protocol
// (publish-in-last-tau, flag, proxy polls, parity xchg buffers, flag
// transitivity) bit-identical to v13.

#define NXc 256
#define NZc 256
#define NTc 400
#define NSc 4
#define NRc 128

#define TS 16                   // steps per epoch = halo depth
#define Bt 32                   // tile edge
#define LROW 64                 // region edge (z)
#define ROWS 64                 // region edge (x)
#define BT 1024                 // threads = 64 rows x 16 strips
#define SPSZ ((ROWS + 2) * LROW) // 4224 per p-buffer (pad row each side)
#define NBLK (NSc * 64)         // 256 blocks
#define NEP (NTc / TS)          // 25 epochs

constexpr float DT_H    = 0.001f;
constexpr float INV_D   = 0.1f;            // 1/DX = 1/DZ
constexpr float SRC_AMP = 0.001f * 0.01f;  // DT/(DX*DZ)
constexpr int   NXZ     = NXc * NZc;

typedef float f32x4 __attribute__((ext_vector_type(4)));

__device__ __forceinline__ unsigned ldu_far(const unsigned* p) {
    unsigned v;
    asm volatile("global_load_dword %0, %1, off sc0 sc1\n\t"
                 "s_waitcnt vmcnt(0)" : "=&v"(v) : "v"(p) : "memory");
    return v;
}
__device__ __forceinline__ void stu_far(unsigned* p, unsigned v) {
    asm volatile("global_store_dword %0, %1, off sc0 sc1"
                 :: "v"(p), "v"(v) : "memory");
}

__global__ __launch_bounds__(BT) void prop_kernel(
    float* __restrict__ xchg, unsigned* __restrict__ flags,
    const float* __restrict__ vp, const float* __restrict__ rho,
    const float* __restrict__ damp, const float* __restrict__ wavelet,
    const int* __restrict__ src_x, const int* __restrict__ src_z,
    const int* __restrict__ rcv_x, const int* __restrict__ rcv_z,
    float* __restrict__ out)
{
    __shared__ float sp[2 * SPSZ];   // double-buffered p (A=0, B=SPSZ)

    const int tid  = threadIdx.x;
    const int bid  = blockIdx.x;
    const int s    = bid >> 6;
    const int tile = bid & 63;
    const int tx = tile >> 3, tz = tile & 7;
    const int gx0 = tx * Bt - TS, gz0 = tz * Bt - TS;

    const int li  = tid >> 4;              // region row 0..63
    const int st  = tid & 15;              // strip 0..15
    const int lk0 = st * 4;
    const int gi  = gx0 + li;
    const int gk0 = gz0 + lk0;             // 4-aligned; strip fully in or out
    const bool in = ((unsigned)gi < (unsigned)NXc) &&
                    ((unsigned)gk0 < (unsigned)NZc);
    const int c4 = s * NXZ + gi * NZc + gk0;
    const bool central = in && ((unsigned)(li - TS) < (unsigned)Bt)
                            && (lk0 >= TS) && (lk0 <= TS + Bt - 4);
    const bool ring = in && !central;

    const size_t F = (size_t)NSc * NXZ;
    float* b0 = xchg;            // epoch parity 0: {p, vx, vz}
    float* b1 = xchg + 3 * F;    // epoch parity 1

    // ---- state + time-invariant coefficients (registers, once) ----
    float pr[4]  = {0, 0, 0, 0};
    float vxr[4] = {0, 0, 0, 0};
    float vzr[4] = {0, 0, 0, 0};
    float vxm[4] = {0, 0, 0, 0};   // shadow: vx of row R-1
    float vzm    = 0.f;            // shadow: vz of cell (gi, gk0-1)
    float fr[4], bxr[4], bzr[4], dkxr[4], dkzr[4], sfr[4];
    float fxm[4], bxm[4];          // row R-1 coefficients
    float fzm = 0.f, bzm = 0.f;    // cell (gi, gk0-1) coefficients
    {
        const int sx = src_x[s], sz = src_z[s];
        if (in) {
            const int g = gi * NZc + gk0;
            float4 r4 = *(const float4*)(rho  + g);
            float4 v4 = *(const float4*)(vp   + g);
            float4 d4 = *(const float4*)(damp + g);
            float rv[4] = {r4.x, r4.y, r4.z, r4.w};
            float vv[4] = {v4.x, v4.y, v4.z, v4.w};
            float dv[4] = {d4.x, d4.y, d4.z, d4.w};
#pragma unroll
            for (int k = 0; k < 4; ++k) {
                int gk = gk0 + k;
                fr[k] = 1.0f - DT_H * dv[k];
                float bi = DT_H / rv[k] * INV_D;
                bxr[k] = (gi == NXc - 1) ? 0.f : bi;   // _dxf zero-pad
                bzr[k] = (gk == NZc - 1) ? 0.f : bi;   // _dzf zero-pad
                float dk = DT_H * rv[k] * vv[k] * vv[k] * INV_D;
                dkxr[k] = (gi == 0) ? 0.f : dk;        // _dxb zero-pad
                dkzr[k] = (gk == 0) ? 0.f : dk;        // _dzb zero-pad
                sfr[k]  = (gi == sx && gk == sz) ? SRC_AMP : 0.f;
            }
            // Row R-1 coefficients (for the vxm shadow). gi-1 <= NX-2 so
            // no dxf mask needed; gi==0 -> zeros (dkxr masks anyway).
            if (gi > 0) {
                float4 rm = *(const float4*)(rho  + g - NZc);
                float4 dm = *(const float4*)(damp + g - NZc);
                float rmv[4] = {rm.x, rm.y, rm.z, rm.w};
                float dmv[4] = {dm.x, dm.y, dm.z, dm.w};
#pragma unroll
                for (int k = 0; k < 4; ++k) {
                    fxm[k] = 1.0f - DT_H * dmv[k];
                    bxm[k] = DT_H / rmv[k] * INV_D;
                }
            } else {
#pragma unroll
                for (int k = 0; k < 4; ++k) { fxm[k] = 0.f; bxm[k] = 0.f; }
            }
            // Cell (gi, gk0-1) coefficients (for the vzm shadow).
            if (gk0 > 0) {
                fzm = 1.0f - DT_H * damp[g - 1];
                bzm = DT_H / rho[g - 1] * INV_D;
            }
        } else {
#pragma unroll
            for (int k = 0; k < 4; ++k) {
                fr[k]=0.f; bxr[k]=0.f; bzr[k]=0.f;
                dkxr[k]=0.f; dkzr[k]=0.f; sfr[k]=0.f;
                fxm[k]=0.f; bxm[k]=0.f;
            }
        }
    }

    const int jp = (li + 1) * LROW + lk0;

    // Zero pad rows of BOTH buffers (steps write rows 0..63 only).
    if (tid < LROW) {
        sp[tid] = 0.f;               sp[SPSZ - LROW + tid] = 0.f;
        sp[SPSZ + tid] = 0.f;        sp[2 * SPSZ - LROW + tid] = 0.f;
    }

    // Receivers (loaded once).
    int rxv = 0, rzv = 0;
    if (tid < NRc) { rxv = rcv_x[tid]; rzv = rcv_z[tid]; }
    const bool rown = (tid < NRc) &&
        ((unsigned)(rxv - tx * Bt) < (unsigned)Bt) &&
        ((unsigned)(rzv - tz * Bt) < (unsigned)Bt);
    const int rj = (rxv - gx0 + 1) * LROW + (rzv - gz0);
    float* obase = out + (size_t)s * NTc * NRc + tid;
    const float* wb = wavelet + s * NTc;

    // Proxy-poll neighbor (tids 0..8, minus center 4).
    int nbid = -1;
    if (tid < 9 && tid != 4) {
        int dx = tid / 3 - 1, dz = tid - (tid / 3) * 3 - 1;
        int nx2 = tx + dx, nz2 = tz + dz;
        if (((unsigned)nx2 < 8u) && ((unsigned)nz2 < 8u))
            nbid = (s << 6) + nx2 * 8 + nz2;
    }

    // One fused step: read old p from rdo buffer, write new p to wro.
    auto STEP = [&](int rdo, int wro, int t, bool pub, float* pb) {
        f32x4 pn = *(const f32x4*)&sp[rdo + jp + LROW];   // old p(R+1)
        f32x4 pm = *(const f32x4*)&sp[rdo + jp - LROW];   // old p(R-1)
        float pze = __shfl_down(pr[0], 1, 64);  // next strip p[0] (old)
        float pmz = __shfl_up(pr[3], 1, 64);    // prev strip p[3] (old)
        // velocities (own) — identical expressions to the shadows' owners
        float pz1[4] = {pr[1], pr[2], pr[3], pze};
#pragma unroll
        for (int k = 0; k < 4; ++k) {
            vxr[k] = fr[k] * vxr[k] - bxr[k] * (pn[k]  - pr[k]);
            vzr[k] = fr[k] * vzr[k] - bzr[k] * (pz1[k] - pr[k]);
        }
        // shadows (neighbor velocities), bit-identical recomputation
#pragma unroll
        for (int k = 0; k < 4; ++k)
            vxm[k] = fxm[k] * vxm[k] - bxm[k] * (pr[k] - pm[k]);
        vzm = fzm * vzm - bzm * (pr[0] - pmz);
        // pressure
        const float wv = wb[t];
        pr[0] = fr[0]*pr[0] - dkxr[0]*(vxr[0]-vxm[0])
              - dkzr[0]*(vzr[0]-vzm) + sfr[0]*wv;
#pragma unroll
        for (int k = 1; k < 4; ++k)
            pr[k] = fr[k]*pr[k] - dkxr[k]*(vxr[k]-vxm[k])
                  - dkzr[k]*(vzr[k]-vzr[k-1]) + sfr[k]*wv;
        // publish overlapped (last tau of epoch only)
        if (pub) {
            f32x4 a = {pr[0], pr[1], pr[2], pr[3]};
            f32x4 b = {vxr[0], vxr[1], vxr[2], vxr[3]};
            f32x4 c = {vzr[0], vzr[1], vzr[2], vzr[3]};
            asm volatile(
                "global_store_dwordx4 %0, %3, off sc0 sc1\n\t"
                "global_store_dwordx4 %1, %4, off sc0 sc1\n\t"
                "global_store_dwordx4 %2, %5, off sc0 sc1"
                :: "v"(pb + c4), "v"(pb + F + c4), "v"(pb + 2 * F + c4),
                   "v"(a), "v"(b), "v"(c)
                : "memory");
        }
        *(f32x4*)&sp[wro + jp] = f32x4{pr[0], pr[1], pr[2], pr[3]};
        __syncthreads();
    };

    for (int l = 0; l < NEP; ++l) {
        const bool notLast = (l < NEP - 1);
        float* pb = (l & 1) ? b1 : b0;

        // ---- epoch setup: p -> A; stage vx in B for shadow init ----
        *(f32x4*)&sp[jp]        = f32x4{pr[0], pr[1], pr[2], pr[3]};
        *(f32x4*)&sp[SPSZ + jp] = f32x4{vxr[0], vxr[1], vxr[2], vxr[3]};
        __syncthreads();
        {
            f32x4 vm = *(const f32x4*)&sp[SPSZ + jp - LROW];
            vxm[0]=vm[0]; vxm[1]=vm[1]; vxm[2]=vm[2]; vxm[3]=vm[3];
            vzm = __shfl_up(vzr[3], 1, 64);
        }
        __syncthreads();   // shadow reads done before step 0 writes to B

        // ---- TS fused steps; parity: even rd=A wr=B, odd rd=B wr=A ----
        const int tb = l * TS;
        for (int t2 = 0; t2 < TS; t2 += 2) {
            STEP(0, SPSZ, tb + t2, false, pb);
            if (tid < NRc && rown)
                obase[(size_t)(tb + t2) * NRc] = sp[SPSZ + rj];
            const bool lastT = (t2 + 2 == TS);
            STEP(SPSZ, 0, tb + t2 + 1,
                 lastT && notLast && central, pb);
            if (!lastT && rown)
                obase[(size_t)(tb + t2 + 1) * NRc] = sp[rj];
        }

        if (notLast) {
            // Release: drain publish stores, then flag.
            asm volatile("s_waitcnt vmcnt(0)" ::: "memory");
            __syncthreads();
            if (tid == 0) stu_far(flags + bid, (unsigned)(l + 1));
            // last-tau receiver record overlaps the polls (final p in A).
            if (rown) obase[(size_t)(tb + TS - 1) * NRc] = sp[rj];
            // Proxy poll: 8 threads watch the 8 neighbors.
            if (nbid >= 0) {
                const unsigned want = (unsigned)(l + 1);
                const unsigned* fp = flags + nbid;
                while (ldu_far(fp) < want) __builtin_amdgcn_s_sleep(2);
            }
            __syncthreads();
            // Ring reload -> regs (epoch setup re-stages LDS + shadows).
            if (ring) {
                f32x4 a, b, c;
                asm volatile(
                    "global_load_dwordx4 %0, %3, off sc0 sc1\n\t"
                    "global_load_dwordx4 %1, %4, off sc0 sc1\n\t"
                    "global_load_dwordx4 %2, %5, off sc0 sc1\n\t"
                    "s_waitcnt vmcnt(0)"
                    : "=&v"(a), "=&v"(b), "=&v"(c)
                    : "v"(pb + c4), "v"(pb + F + c4), "v"(pb + 2 * F + c4)
                    : "memory");
                pr[0]=a.x; pr[1]=a.y; pr[2]=a.z; pr[3]=a.w;
                vxr[0]=b.x; vxr[1]=b.y; vxr[2]=b.z; vxr[3]=b.w;
                vzr[0]=c.x; vzr[1]=c.y; vzr[2]=c.z; vzr[3]=c.w;
            }
        } else {
            if (rown) obase[(size_t)(tb + TS - 1) * NRc] = sp[rj];
        }
    }
}

extern "C" void kernel_launch(void* const* d_in, const int* in_sizes, int n_in,
                              void* d_out, int out_size, void* d_ws, size_t ws_size,
                              hipStream_t stream)
{
    const float* vp      = (const float*)d_in[0];
    const float* rho     = (const float*)d_in[1];
    const float* damp    = (const float*)d_in[2];
    const float* wavelet = (const float*)d_in[3];
    const int*   src_x   = (const int*)d_in[4];
    const int*   src_z   = (const int*)d_in[5];
    const int*   rcv_x   = (const int*)d_in[6];
    const int*   rcv_z   = (const int*)d_in[7];
    float* out = (float*)d_out;
    float* ws  = (float*)d_ws;

    const size_t F = (size_t)NSc * NXZ;
    float* xchg = ws;                              // 6 fields (2 parities)
    unsigned* flags = (unsigned*)(ws + 6 * F);     // 256 epoch counters

    // Flags must start at 0 every call (ws poisoned once, not re-poisoned).
    hipMemsetAsync(flags, 0, NBLK * sizeof(unsigned), stream);

    prop_kernel<<<NBLK, BT, 0, stream>>>(
        xchg, flags, vp, rho, damp, wavelet,
        src_x, src_z, rcv_x, rcv_z, out);
}